// Round 4
// baseline (361.859 us; speedup 1.0000x reference)
//
#include <hip/hip_runtime.h>
#include <cmath>

// ---------------------------------------------------------------------------
// Classifier pipeline. Main GEMMs fp16x1 (round-2 m97 structure, 852 TF
// measured); argmax protected by fp16x2 correction chain on flagged rows
// (top-2 gap < TAU).
//
// d_out byte layout (total 165,412,864 B):
//   feats [8192,1024] f32 @ 0
//   aug   [8192,1024] f32 @ 33,554,432
//   o1    [8192,1000] f32 @ 67,108,864
//   o2    [8192,1000] f32 @ 99,876,864
//   smx   [8192,1000] f32 @ 132,644,864
//
// Scratch (dead-region hosted; lifetime [first-write .. last-read]):
//   fh    fp16[8192*2048] @  67,108,864  [splitF .. G1]      (o1 slot)
//   fetsh fp16[8192*1024] @  33,554,432  [G1 .. G2]          (aug lo half)
//   idx   int[2048]       @  50,331,648  [masksm .. fixup]   (aug hi half)
//   cnt   int             @  50,339,840  [memset .. fixup]
//   fgsh  fp16[2048*1024] @  50,348,032  [gG1 .. gG2]
//   fgsl  fp16[2048*1024] @  54,542,336  [gG1 .. gG2]
//   o1g   f32 [2048*1000] @  58,736,640  [gG2 .. fixup]      (ends 66,928,640)
//   sm1h  fp16[8192*1024] @  99,876,864  [masksm .. G3]      (o2 slot)
//   cth   fp16[1024*1024] @ 116,654,080  [ctrans .. G3]
//   wbh   fp16[1024*2048] @ 118,751,232  [splitWb .. gG1]
//   wbl   fp16[1024*2048] @ 122,945,536  [splitWb .. gG1]    (ends 127,139,840)
//   w2h   fp16[1024*1024] @ 132,644,864  [padW2 .. G4]       (smx slot)
//   w1h   fp16[1024*1024] @ 142,606,336  [padW1 .. gG2]
//   w1l   fp16[1024*1024] @ 144,703,488  [padW1 .. gG2]
//   fgh   fp16[2048*2048] @ 146,800,640  [gsplit .. gG1]     (xh slot)
//   fgl   fp16[2048*2048] @ 155,189,248  [gsplit .. gG1]     (ends 163,577,856)
//   xh    fp16[8192*1024] @ 146,800,640  [rownorm .. G4]
// ---------------------------------------------------------------------------

typedef _Float16 h8 __attribute__((ext_vector_type(8)));
typedef _Float16 h4 __attribute__((ext_vector_type(4)));
typedef float f32x4 __attribute__((ext_vector_type(4)));

#define TAU 0.015f
#define CAP 2048

__device__ __forceinline__ void gload_lds16(const _Float16* g, _Float16* l) {
    __builtin_amdgcn_global_load_lds(
        (const __attribute__((address_space(1))) void*)g,
        (__attribute__((address_space(3))) void*)l, 16, 0, 0);
}

// MODE 1: fp16x1  C = A@B^T + bias(aux); also Ch=fp16(C)      (main G1)
// MODE 2: fp16x1  C = A@B^T, cols<nC                          (main G2)
// MODE 3: fp16x1  C = A@B^T + aux[row,col]                    (main G3)
// MODE 4: fp16x1  C = A@B^T * 20, cols<nC                     (main G4)
// MODE 5: fp16x2  Ch/Cl = split(A@B^T + bias), no f32 C       (gather G1)
// MODE 6: fp16x2  C = A@B^T, cols<nC                          (gather G2)
template <int MODE>
__global__ __launch_bounds__(256, (MODE >= 5) ? 2 : 4) void gemm16(
    const _Float16* __restrict__ Ah, const _Float16* __restrict__ Al, int lda,
    const _Float16* __restrict__ Bh, const _Float16* __restrict__ Bl, int ldb,
    int K,
    float* __restrict__ C, int ldc, int nC,
    const float* __restrict__ aux,
    _Float16* __restrict__ Ch, _Float16* __restrict__ Cl,
    const int* __restrict__ cnt)
{
    constexpr bool P2 = (MODE >= 5);
    __shared__ _Float16 sAh[128 * 64];
    __shared__ _Float16 sBh[128 * 64];
    __shared__ _Float16 sAl[P2 ? 128 * 64 : 8];
    __shared__ _Float16 sBl[P2 ? 128 * 64 : 8];

    const int t = threadIdx.x;
    const int lane = t & 63, wid = t >> 6;
    int row0, col0;
    if constexpr (MODE >= 5) {
        row0 = blockIdx.y * 128; col0 = blockIdx.x * 128;
        if (row0 >= *cnt) return;              // correction rows only
    } else {
        // T1: bijective XCD swizzle (512 wgs, 64/XCD -> 8 row-panels x 8 col)
        const int wg = blockIdx.x;
        const int wgid = (wg & 7) * 64 + (wg >> 3);
        row0 = (wgid >> 3) * 128; col0 = (wgid & 7) * 128;
    }
    const int wr = wid >> 1, wc = wid & 1;     // 2x2 waves -> 64x64 out each
    const int fr = lane & 15;
    const int fk = (lane >> 4) * 8;
    const int srow = lane >> 3;                // staging: 8 lanes/row
    const int scol = (lane & 7) * 8;           // 16B per lane

    f32x4 acc[4][4] = {};
    f32x4 accc[4][4] = {};                     // cross terms (x2048); DCE'd if !P2

    for (int k0 = 0; k0 < K; k0 += 64) {
        #pragma unroll
        for (int j = 0; j < 4; ++j) {
            int i = wid * 4 + j;
            int r = i * 8 + srow;
            const size_t ga = (size_t)(row0 + r) * lda + k0 + scol;
            const size_t gb = (size_t)(col0 + r) * ldb + k0 + scol;
            gload_lds16(Ah + ga, &sAh[i * 512]);
            gload_lds16(Bh + gb, &sBh[i * 512]);
            if constexpr (P2) {
                gload_lds16(Al + ga, &sAl[i * 512]);
                gload_lds16(Bl + gb, &sBl[i * 512]);
            }
        }
        __syncthreads();
        #pragma unroll
        for (int ks = 0; ks < 2; ++ks) {
            h8 ah[4], al[4];
            #pragma unroll
            for (int mf = 0; mf < 4; ++mf) {
                int rr = wr * 64 + mf * 16 + fr;
                ah[mf] = *(const h8*)&sAh[rr * 64 + ks * 32 + fk];
                if constexpr (P2) al[mf] = *(const h8*)&sAl[rr * 64 + ks * 32 + fk];
            }
            #pragma unroll
            for (int nf = 0; nf < 4; ++nf) {
                int cc = wc * 64 + nf * 16 + fr;
                h8 bh = *(const h8*)&sBh[cc * 64 + ks * 32 + fk];
                h8 bl;
                if constexpr (P2) bl = *(const h8*)&sBl[cc * 64 + ks * 32 + fk];
                #pragma unroll
                for (int mf = 0; mf < 4; ++mf) {
                    acc[mf][nf] = __builtin_amdgcn_mfma_f32_16x16x32_f16(ah[mf], bh, acc[mf][nf], 0, 0, 0);
                    if constexpr (P2) {
                        accc[mf][nf] = __builtin_amdgcn_mfma_f32_16x16x32_f16(ah[mf], bl, accc[mf][nf], 0, 0, 0);
                        accc[mf][nf] = __builtin_amdgcn_mfma_f32_16x16x32_f16(al[mf], bh, accc[mf][nf], 0, 0, 0);
                    }
                }
            }
        }
        __syncthreads();
    }
    // ---- epilogue (C/D: col=lane&15, row=(lane>>4)*4+j) ----
    #pragma unroll
    for (int mf = 0; mf < 4; ++mf) {
        #pragma unroll
        for (int nf = 0; nf < 4; ++nf) {
            f32x4 v = acc[mf][nf];
            if constexpr (P2) v = v + accc[mf][nf] * (1.0f / 2048.0f);
            const int gcol = col0 + wc * 64 + nf * 16 + fr;
            const int rbase = row0 + wr * 64 + mf * 16 + (lane >> 4) * 4;
            #pragma unroll
            for (int j = 0; j < 4; ++j) {
                const int grow = rbase + j;
                float val = v[j];
                if constexpr (MODE == 1 || MODE == 5) val += aux[gcol];
                if constexpr (MODE == 3) val += aux[(size_t)grow * 1024 + gcol];
                if constexpr (MODE == 4) val *= 20.0f;
                if constexpr (MODE == 5) {
                    _Float16 h = (_Float16)val;
                    Ch[(size_t)grow * 1024 + gcol] = h;
                    Cl[(size_t)grow * 1024 + gcol] = (_Float16)((val - (float)h) * 2048.0f);
                } else {
                    if (gcol < nC) {
                        C[(size_t)grow * ldc + gcol] = val;
                        if constexpr (MODE == 1)
                            Ch[(size_t)grow * 1024 + gcol] = (_Float16)val;
                    }
                }
            }
        }
    }
}

// fp32 -> fp16 (hi only)
__global__ void conv_kernel(const float* __restrict__ src, _Float16* __restrict__ hi, int n4)
{
    for (int i = blockIdx.x * 256 + threadIdx.x; i < n4; i += gridDim.x * 256) {
        f32x4 v = ((const f32x4*)src)[i];
        h4 h;
        #pragma unroll
        for (int j = 0; j < 4; ++j) h[j] = (_Float16)v[j];
        ((h4*)hi)[i] = h;
    }
}

// fp32 -> fp16 hi/lo split (lo scaled x2048)
__global__ void split_kernel(const float* __restrict__ src,
                             _Float16* __restrict__ hi, _Float16* __restrict__ lo, int n4)
{
    for (int i = blockIdx.x * 256 + threadIdx.x; i < n4; i += gridDim.x * 256) {
        f32x4 v = ((const f32x4*)src)[i];
        h4 h, l;
        #pragma unroll
        for (int j = 0; j < 4; ++j) {
            _Float16 hh = (_Float16)v[j];
            h[j] = hh;
            l[j] = (_Float16)((v[j] - (float)hh) * 2048.0f);
        }
        ((h4*)hi)[i] = h;
        ((h4*)lo)[i] = l;
    }
}

// fp32 [nrows,1024] -> fp16 hi(/lo) padded to [1024,1024]
template <bool LO>
__global__ void padsplit_kernel(const float* __restrict__ src,
                                _Float16* __restrict__ hi, _Float16* __restrict__ lo, int nrows)
{
    for (int i = blockIdx.x * 256 + threadIdx.x; i < 1024 * 256; i += gridDim.x * 256) {
        int r = i >> 8;
        f32x4 v = {0.f, 0.f, 0.f, 0.f};
        if (r < nrows) v = ((const f32x4*)src)[i];
        h4 h, l;
        #pragma unroll
        for (int j = 0; j < 4; ++j) {
            _Float16 hh = (_Float16)v[j];
            h[j] = hh;
            if constexpr (LO) l[j] = (_Float16)((v[j] - (float)hh) * 2048.0f);
        }
        ((h4*)hi)[i] = h;
        if constexpr (LO) ((h4*)lo)[i] = l;
    }
}

// cT[n][k] = k<1000 ? fp16(centroid[k][n]) : 0
__global__ __launch_bounds__(256) void ctrans_kernel(const float* __restrict__ centroid,
                                                     _Float16* __restrict__ cT)
{
    __shared__ float tile[32][33];
    const int t = threadIdx.x;
    const int tx = t & 31, ty = t >> 5;
    const int k0 = blockIdx.y * 32, n0 = blockIdx.x * 32;
    #pragma unroll
    for (int p = 0; p < 4; ++p) {
        int k = k0 + ty + p * 8;
        tile[ty + p * 8][tx] = (k < 1000) ? centroid[(size_t)k * 1024 + n0 + tx] : 0.0f;
    }
    __syncthreads();
    #pragma unroll
    for (int p = 0; p < 4; ++p) {
        int n = n0 + ty + p * 8;
        cT[(size_t)n * 1024 + k0 + tx] = (_Float16)tile[tx][ty + p * 8];
    }
}

// shared device body: masked softmax given logits x (len 1000) -> fp16 row y
__device__ __forceinline__ void masked_softmax_body(
    const float* __restrict__ x, _Float16* __restrict__ y,
    int t, float* wv, int* wi, int* flag_row, int* d_idx, int* d_cnt, int rowid)
{
    // ---- top-2 (value) + argmax(first-occurrence) ----
    float bv = -1e30f, sv = -1e30f; int bi = 0;
    for (int c = t; c < 1000; c += 256) {
        float v = x[c];
        if (v > bv) { sv = bv; bv = v; bi = c; }
        else if (v > sv) sv = v;
    }
    #pragma unroll
    for (int off = 32; off > 0; off >>= 1) {
        float ov = __shfl_down(bv, off, 64);
        int   oi = __shfl_down(bi, off, 64);
        float os = __shfl_down(sv, off, 64);
        if (ov > bv || (ov == bv && oi < bi)) {
            sv = fmaxf(bv, os); bv = ov; bi = oi;
        } else {
            sv = fmaxf(sv, fmaxf(ov, os) == ov ? ov : os);  // max of remaining
            sv = fmaxf(sv, ov); sv = fmaxf(sv, os);
        }
        // note: redundant fmaxf keeps logic simple & correct: second = max of all non-best
    }
    __shared__ float svv[4];
    const int lane = t & 63, wid = t >> 6;
    if (lane == 0) { wv[wid] = bv; wi[wid] = bi; svv[wid] = sv; }
    __syncthreads();
    __shared__ float s_m, s_tot; __shared__ int s_p;
    if (t == 0) {
        float mv = wv[0]; int mi = wi[0]; float m2 = svv[0];
        for (int w = 1; w < 4; ++w) {
            if (wv[w] > mv || (wv[w] == mv && wi[w] < mi)) {
                m2 = fmaxf(mv, svv[w]); mv = wv[w]; mi = wi[w];
            } else {
                m2 = fmaxf(m2, fmaxf(wv[w], svv[w]));
            }
        }
        s_p = mi; s_m = mv;
        if (flag_row && (mv - m2) < TAU) {     // ambiguous: queue precise recompute
            int slot = atomicAdd(d_cnt, 1);
            if (slot < CAP) d_idx[slot] = rowid;
        }
    }
    __syncthreads();
    const int p = s_p; const float m = s_m;
    if (p >= 500) {
        for (int c = t; c < 1024; c += 256) y[c] = (c == p) ? (_Float16)1.0f : (_Float16)0.0f;
    } else {
        float s = 0.f;
        for (int c = t; c < 1000; c += 256)
            if (c == p || c >= 500) s += expf(x[c] - m);
        #pragma unroll
        for (int off = 32; off > 0; off >>= 1) s += __shfl_down(s, off, 64);
        if (lane == 0) wv[wid] = s;
        __syncthreads();
        if (t == 0) s_tot = wv[0] + wv[1] + wv[2] + wv[3];
        __syncthreads();
        const float inv = 1.0f / s_tot;
        for (int c = t; c < 1024; c += 256) {
            float v = 0.f;
            if (c < 1000 && (c == p || c >= 500)) v = expf(x[c] - m) * inv;
            y[c] = (_Float16)v;
        }
    }
}

__global__ __launch_bounds__(256) void masksm_kernel(const float* __restrict__ o1,
                                                     _Float16* __restrict__ sm,
                                                     int* __restrict__ d_idx,
                                                     int* __restrict__ d_cnt)
{
    __shared__ float wv[4]; __shared__ int wi[4];
    const int row = blockIdx.x;
    int dummy;
    masked_softmax_body(o1 + (size_t)row * 1000, sm + (size_t)row * 1024,
                        threadIdx.x, wv, wi, &dummy, d_idx, d_cnt, row);
}

// precise rewrite of flagged rows from o1g
__global__ __launch_bounds__(256) void fixup_kernel(const float* __restrict__ o1g,
                                                    _Float16* __restrict__ sm,
                                                    const int* __restrict__ d_idx,
                                                    const int* __restrict__ d_cnt)
{
    const int slot = blockIdx.x;
    if (slot >= *d_cnt || slot >= CAP) return;
    const int row = d_idx[slot];
    __shared__ float wv[4]; __shared__ int wi[4];
    masked_softmax_body(o1g + (size_t)slot * 1000, sm + (size_t)row * 1024,
                        threadIdx.x, wv, wi, nullptr, nullptr, nullptr, 0);
}

// gather flagged feature rows -> fp16 hi/lo split [CAP x 2048]
__global__ __launch_bounds__(256) void gather_split_kernel(
    const float* __restrict__ features,
    _Float16* __restrict__ fgh, _Float16* __restrict__ fgl,
    const int* __restrict__ d_idx, const int* __restrict__ d_cnt)
{
    const int slot = blockIdx.x;
    if (slot >= *d_cnt || slot >= CAP) return;
    const int row = d_idx[slot];
    const int t = threadIdx.x;
    #pragma unroll
    for (int q = 0; q < 2; ++q) {
        int o = t * 8 + q * 4;   // 0..2047
        f32x4 v = *(const f32x4*)(features + (size_t)row * 2048 + o);
        h4 h, l;
        #pragma unroll
        for (int j = 0; j < 4; ++j) {
            _Float16 hh = (_Float16)v[j];
            h[j] = hh;
            l[j] = (_Float16)((v[j] - (float)hh) * 2048.0f);
        }
        *(h4*)(fgh + (size_t)slot * 2048 + o) = h;
        *(h4*)(fgl + (size_t)slot * 2048 + o) = l;
    }
}

// fused: invn = 1/max(||aug_row||,eps); xh = fp16(aug * invn)
__global__ __launch_bounds__(256) void rownorm_x_kernel(const float* __restrict__ aug,
                                                        _Float16* __restrict__ xh)
{
    const int row = blockIdx.x; const int t = threadIdx.x;
    f32x4 v = *((const f32x4*)(aug + (size_t)row * 1024) + t);
    float s = v[0]*v[0] + v[1]*v[1] + v[2]*v[2] + v[3]*v[3];
    #pragma unroll
    for (int off = 32; off > 0; off >>= 1) s += __shfl_down(s, off, 64);
    __shared__ float ws4[4]; __shared__ float s_inv;
    const int lane = t & 63, wid = t >> 6;
    if (lane == 0) ws4[wid] = s;
    __syncthreads();
    if (t == 0) {
        float tot = ws4[0] + ws4[1] + ws4[2] + ws4[3];
        s_inv = 1.0f / fmaxf(sqrtf(tot), 1e-12f);
    }
    __syncthreads();
    const float inv = s_inv;
    h4 h;
    #pragma unroll
    for (int j = 0; j < 4; ++j) h[j] = (_Float16)(v[j] * inv);
    *((h4*)(xh + (size_t)row * 1024) + t) = h;
}

// plain row softmax over 1000
__global__ __launch_bounds__(256) void softmax2_kernel(const float* __restrict__ o2,
                                                       float* __restrict__ out)
{
    const int row = blockIdx.x; const int t = threadIdx.x;
    const float* x = o2 + (size_t)row * 1000;
    float* y = out + (size_t)row * 1000;
    float m = -1e30f;
    for (int c = t; c < 1000; c += 256) m = fmaxf(m, x[c]);
    #pragma unroll
    for (int off = 32; off > 0; off >>= 1) m = fmaxf(m, __shfl_down(m, off, 64));
    __shared__ float sm4[4]; __shared__ float s_m, s_s;
    const int lane = t & 63, wid = t >> 6;
    if (lane == 0) sm4[wid] = m;
    __syncthreads();
    if (t == 0) s_m = fmaxf(fmaxf(sm4[0], sm4[1]), fmaxf(sm4[2], sm4[3]));
    __syncthreads();
    m = s_m;
    float s = 0.f;
    for (int c = t; c < 1000; c += 256) s += expf(x[c] - m);
    #pragma unroll
    for (int off = 32; off > 0; off >>= 1) s += __shfl_down(s, off, 64);
    if (lane == 0) sm4[wid] = s;
    __syncthreads();
    if (t == 0) s_s = sm4[0] + sm4[1] + sm4[2] + sm4[3];
    __syncthreads();
    const float inv = 1.0f / s_s;
    for (int c = t; c < 1000; c += 256) y[c] = expf(x[c] - m) * inv;
}

extern "C" void kernel_launch(void* const* d_in, const int* in_sizes, int n_in,
                              void* d_out, int out_size, void* d_ws, size_t ws_size,
                              hipStream_t stream)
{
    const float* features = (const float*)d_in[0];  // [8192,2048]
    const float* W_b      = (const float*)d_in[1];  // [1024,2048]
    const float* b_b      = (const float*)d_in[2];  // [1024]
    const float* W1       = (const float*)d_in[3];  // [1000,1024]
    const float* W2       = (const float*)d_in[4];  // [1000,1024]
    const float* centroid = (const float*)d_in[5];  // [1000,1024]

    char* base = (char*)d_out;
    float* feats = (float*)(base);
    float* aug   = (float*)(base + 33554432);
    float* o1    = (float*)(base + 67108864);
    float* o2    = (float*)(base + 99876864);
    float* smx   = (float*)(base + 132644864);

    _Float16* fh    = (_Float16*)(base + 67108864);
    _Float16* fetsh = (_Float16*)(base + 33554432);
    int*      idx   = (int*)     (base + 50331648);
    int*      cnt   = (int*)     (base + 50339840);
    _Float16* fgsh  = (_Float16*)(base + 50348032);
    _Float16* fgsl  = (_Float16*)(base + 54542336);
    float*    o1g   = (float*)   (base + 58736640);
    _Float16* sm1h  = (_Float16*)(base + 99876864);
    _Float16* cth   = (_Float16*)(base + 116654080);
    _Float16* wbh   = (_Float16*)(base + 118751232);
    _Float16* wbl   = (_Float16*)(base + 122945536);
    _Float16* w2h   = (_Float16*)(base + 132644864);
    _Float16* w1h   = (_Float16*)(base + 142606336);
    _Float16* w1l   = (_Float16*)(base + 144703488);
    _Float16* fgh   = (_Float16*)(base + 146800640);
    _Float16* fgl   = (_Float16*)(base + 155189248);
    _Float16* xh    = (_Float16*)(base + 146800640);

    hipMemsetAsync(cnt, 0, 4, stream);

    // conversions
    conv_kernel<<<2048, 256, 0, stream>>>(features, fh, 4194304);
    split_kernel<<<1024, 256, 0, stream>>>(W_b, wbh, wbl, 524288);
    padsplit_kernel<true><<<1024, 256, 0, stream>>>(W1, w1h, w1l, 1000);
    ctrans_kernel<<<dim3(32, 32), 256, 0, stream>>>(centroid, cth);
    padsplit_kernel<false><<<1024, 256, 0, stream>>>(W2, w2h, nullptr, 1000);

    // G1: feats = F@W_b^T + b_b (fp16x1); epilogue also emits fetsh
    gemm16<1><<<512, 256, 0, stream>>>(fh, nullptr, 2048, wbh, nullptr, 2048, 2048,
                                       feats, 1024, 1024, b_b, fetsh, nullptr, nullptr);
    // G2: o1 = feats@W1^T (fp16x1)
    gemm16<2><<<512, 256, 0, stream>>>(fetsh, nullptr, 1024, w1h, nullptr, 1024, 1024,
                                       o1, 1000, 1000, nullptr, nullptr, nullptr, nullptr);
    // masked softmax + ambiguity flagging
    masksm_kernel<<<8192, 256, 0, stream>>>(o1, sm1h, idx, cnt);

    // correction chain (flagged rows only; blocks early-exit on cnt)
    gather_split_kernel<<<CAP, 256, 0, stream>>>(features, fgh, fgl, idx, cnt);
    gemm16<5><<<dim3(8, CAP / 128), 256, 0, stream>>>(fgh, fgl, 2048, wbh, wbl, 2048, 2048,
                                                      nullptr, 0, 1024, b_b, fgsh, fgsl, cnt);
    gemm16<6><<<dim3(8, CAP / 128), 256, 0, stream>>>(fgsh, fgsl, 1024, w1h, w1l, 1024, 1024,
                                                      o1g, 1000, 1000, nullptr, nullptr, nullptr, cnt);
    fixup_kernel<<<CAP, 256, 0, stream>>>(o1g, sm1h, idx, cnt);

    // G3: aug = sm1@centroid + feats (fp16x1)
    gemm16<3><<<512, 256, 0, stream>>>(sm1h, nullptr, 1024, cth, nullptr, 1024, 1024,
                                       aug, 1024, 1024, feats, nullptr, nullptr, nullptr);
    rownorm_x_kernel<<<8192, 256, 0, stream>>>(aug, xh);
    // G4: o2 = x@W2^T * 20 (fp16x1)
    gemm16<4><<<512, 256, 0, stream>>>(xh, nullptr, 1024, w2h, nullptr, 1024, 1024,
                                       o2, 1000, 1000, nullptr, nullptr, nullptr, nullptr);
    softmax2_kernel<<<8192, 256, 0, stream>>>(o2, smx);
}

// Round 5
// 361.306 us; speedup vs baseline: 1.0015x; 1.0015x over previous
//
#include <hip/hip_runtime.h>
#include <cmath>

// ---------------------------------------------------------------------------
// Classifier pipeline. Main GEMMs fp16x1 (round-2 m97 structure, 852 TF
// measured); argmax protected by fp16x2 correction chain on flagged rows
// (top-2 gap < TAU). Round 5: hipMemsetAsync(cnt) -> zero_cnt kernel
// (the graph memset node materialized as a ~95us 661MB fillBufferAligned
// per replay in round 4).
//
// d_out byte layout (total 165,412,864 B):
//   feats [8192,1024] f32 @ 0
//   aug   [8192,1024] f32 @ 33,554,432
//   o1    [8192,1000] f32 @ 67,108,864
//   o2    [8192,1000] f32 @ 99,876,864
//   smx   [8192,1000] f32 @ 132,644,864
//
// Scratch (dead-region hosted; lifetime [first-write .. last-read]):
//   fh    fp16[8192*2048] @  67,108,864  [splitF .. G1]      (o1 slot)
//   fetsh fp16[8192*1024] @  33,554,432  [G1 .. G2]          (aug lo half)
//   idx   int[2048]       @  50,331,648  [masksm .. fixup]   (aug hi half)
//   cnt   int             @  50,339,840  [zero .. fixup]
//   fgsh  fp16[2048*1024] @  50,348,032  [gG1 .. gG2]
//   fgsl  fp16[2048*1024] @  54,542,336  [gG1 .. gG2]
//   o1g   f32 [2048*1000] @  58,736,640  [gG2 .. fixup]      (ends 66,928,640)
//   sm1h  fp16[8192*1024] @  99,876,864  [masksm .. G3]      (o2 slot)
//   cth   fp16[1024*1024] @ 116,654,080  [ctrans .. G3]
//   wbh   fp16[1024*2048] @ 118,751,232  [splitWb .. gG1]
//   wbl   fp16[1024*2048] @ 122,945,536  [splitWb .. gG1]    (ends 127,139,840)
//   w2h   fp16[1024*1024] @ 132,644,864  [padW2 .. G4]       (smx slot)
//   w1h   fp16[1024*1024] @ 142,606,336  [padW1 .. gG2]
//   w1l   fp16[1024*1024] @ 144,703,488  [padW1 .. gG2]
//   fgh   fp16[2048*2048] @ 146,800,640  [gsplit .. gG1]     (xh slot)
//   fgl   fp16[2048*2048] @ 155,189,248  [gsplit .. gG1]     (ends 163,577,856)
//   xh    fp16[8192*1024] @ 146,800,640  [rownorm .. G4]
// ---------------------------------------------------------------------------

typedef _Float16 h8 __attribute__((ext_vector_type(8)));
typedef _Float16 h4 __attribute__((ext_vector_type(4)));
typedef float f32x4 __attribute__((ext_vector_type(4)));

#define TAU 0.015f
#define CAP 2048

__device__ __forceinline__ void gload_lds16(const _Float16* g, _Float16* l) {
    __builtin_amdgcn_global_load_lds(
        (const __attribute__((address_space(1))) void*)g,
        (__attribute__((address_space(3))) void*)l, 16, 0, 0);
}

__global__ void zero_cnt_kernel(int* __restrict__ cnt) { *cnt = 0; }

// MODE 1: fp16x1  C = A@B^T + bias(aux); also Ch=fp16(C)      (main G1)
// MODE 2: fp16x1  C = A@B^T, cols<nC                          (main G2)
// MODE 3: fp16x1  C = A@B^T + aux[row,col]                    (main G3)
// MODE 4: fp16x1  C = A@B^T * 20, cols<nC                     (main G4)
// MODE 5: fp16x2  Ch/Cl = split(A@B^T + bias), no f32 C       (gather G1)
// MODE 6: fp16x2  C = A@B^T, cols<nC                          (gather G2)
template <int MODE>
__global__ __launch_bounds__(256, (MODE >= 5) ? 2 : 4) void gemm16(
    const _Float16* __restrict__ Ah, const _Float16* __restrict__ Al, int lda,
    const _Float16* __restrict__ Bh, const _Float16* __restrict__ Bl, int ldb,
    int K,
    float* __restrict__ C, int ldc, int nC,
    const float* __restrict__ aux,
    _Float16* __restrict__ Ch, _Float16* __restrict__ Cl,
    const int* __restrict__ cnt)
{
    constexpr bool P2 = (MODE >= 5);
    __shared__ _Float16 sAh[128 * 64];
    __shared__ _Float16 sBh[128 * 64];
    __shared__ _Float16 sAl[P2 ? 128 * 64 : 8];
    __shared__ _Float16 sBl[P2 ? 128 * 64 : 8];

    const int t = threadIdx.x;
    const int lane = t & 63, wid = t >> 6;
    int row0, col0;
    if constexpr (MODE >= 5) {
        row0 = blockIdx.y * 128; col0 = blockIdx.x * 128;
        if (row0 >= *cnt) return;              // correction rows only
    } else {
        // T1: bijective XCD swizzle (512 wgs, 64/XCD -> 8 row-panels x 8 col)
        const int wg = blockIdx.x;
        const int wgid = (wg & 7) * 64 + (wg >> 3);
        row0 = (wgid >> 3) * 128; col0 = (wgid & 7) * 128;
    }
    const int wr = wid >> 1, wc = wid & 1;     // 2x2 waves -> 64x64 out each
    const int fr = lane & 15;
    const int fk = (lane >> 4) * 8;
    const int srow = lane >> 3;                // staging: 8 lanes/row
    const int scol = (lane & 7) * 8;           // 16B per lane

    f32x4 acc[4][4] = {};
    f32x4 accc[4][4] = {};                     // cross terms (x2048); DCE'd if !P2

    for (int k0 = 0; k0 < K; k0 += 64) {
        #pragma unroll
        for (int j = 0; j < 4; ++j) {
            int i = wid * 4 + j;
            int r = i * 8 + srow;
            const size_t ga = (size_t)(row0 + r) * lda + k0 + scol;
            const size_t gb = (size_t)(col0 + r) * ldb + k0 + scol;
            gload_lds16(Ah + ga, &sAh[i * 512]);
            gload_lds16(Bh + gb, &sBh[i * 512]);
            if constexpr (P2) {
                gload_lds16(Al + ga, &sAl[i * 512]);
                gload_lds16(Bl + gb, &sBl[i * 512]);
            }
        }
        __syncthreads();
        #pragma unroll
        for (int ks = 0; ks < 2; ++ks) {
            h8 ah[4], al[4];
            #pragma unroll
            for (int mf = 0; mf < 4; ++mf) {
                int rr = wr * 64 + mf * 16 + fr;
                ah[mf] = *(const h8*)&sAh[rr * 64 + ks * 32 + fk];
                if constexpr (P2) al[mf] = *(const h8*)&sAl[rr * 64 + ks * 32 + fk];
            }
            #pragma unroll
            for (int nf = 0; nf < 4; ++nf) {
                int cc = wc * 64 + nf * 16 + fr;
                h8 bh = *(const h8*)&sBh[cc * 64 + ks * 32 + fk];
                h8 bl;
                if constexpr (P2) bl = *(const h8*)&sBl[cc * 64 + ks * 32 + fk];
                #pragma unroll
                for (int mf = 0; mf < 4; ++mf) {
                    acc[mf][nf] = __builtin_amdgcn_mfma_f32_16x16x32_f16(ah[mf], bh, acc[mf][nf], 0, 0, 0);
                    if constexpr (P2) {
                        accc[mf][nf] = __builtin_amdgcn_mfma_f32_16x16x32_f16(ah[mf], bl, accc[mf][nf], 0, 0, 0);
                        accc[mf][nf] = __builtin_amdgcn_mfma_f32_16x16x32_f16(al[mf], bh, accc[mf][nf], 0, 0, 0);
                    }
                }
            }
        }
        __syncthreads();
    }
    // ---- epilogue (C/D: col=lane&15, row=(lane>>4)*4+j) ----
    #pragma unroll
    for (int mf = 0; mf < 4; ++mf) {
        #pragma unroll
        for (int nf = 0; nf < 4; ++nf) {
            f32x4 v = acc[mf][nf];
            if constexpr (P2) v = v + accc[mf][nf] * (1.0f / 2048.0f);
            const int gcol = col0 + wc * 64 + nf * 16 + fr;
            const int rbase = row0 + wr * 64 + mf * 16 + (lane >> 4) * 4;
            #pragma unroll
            for (int j = 0; j < 4; ++j) {
                const int grow = rbase + j;
                float val = v[j];
                if constexpr (MODE == 1 || MODE == 5) val += aux[gcol];
                if constexpr (MODE == 3) val += aux[(size_t)grow * 1024 + gcol];
                if constexpr (MODE == 4) val *= 20.0f;
                if constexpr (MODE == 5) {
                    _Float16 h = (_Float16)val;
                    Ch[(size_t)grow * 1024 + gcol] = h;
                    Cl[(size_t)grow * 1024 + gcol] = (_Float16)((val - (float)h) * 2048.0f);
                } else {
                    if (gcol < nC) {
                        C[(size_t)grow * ldc + gcol] = val;
                        if constexpr (MODE == 1)
                            Ch[(size_t)grow * 1024 + gcol] = (_Float16)val;
                    }
                }
            }
        }
    }
}

// fp32 -> fp16 (hi only)
__global__ void conv_kernel(const float* __restrict__ src, _Float16* __restrict__ hi, int n4)
{
    for (int i = blockIdx.x * 256 + threadIdx.x; i < n4; i += gridDim.x * 256) {
        f32x4 v = ((const f32x4*)src)[i];
        h4 h;
        #pragma unroll
        for (int j = 0; j < 4; ++j) h[j] = (_Float16)v[j];
        ((h4*)hi)[i] = h;
    }
}

// fp32 -> fp16 hi/lo split (lo scaled x2048)
__global__ void split_kernel(const float* __restrict__ src,
                             _Float16* __restrict__ hi, _Float16* __restrict__ lo, int n4)
{
    for (int i = blockIdx.x * 256 + threadIdx.x; i < n4; i += gridDim.x * 256) {
        f32x4 v = ((const f32x4*)src)[i];
        h4 h, l;
        #pragma unroll
        for (int j = 0; j < 4; ++j) {
            _Float16 hh = (_Float16)v[j];
            h[j] = hh;
            l[j] = (_Float16)((v[j] - (float)hh) * 2048.0f);
        }
        ((h4*)hi)[i] = h;
        ((h4*)lo)[i] = l;
    }
}

// fp32 [nrows,1024] -> fp16 hi(/lo) padded to [1024,1024]
template <bool LO>
__global__ void padsplit_kernel(const float* __restrict__ src,
                                _Float16* __restrict__ hi, _Float16* __restrict__ lo, int nrows)
{
    for (int i = blockIdx.x * 256 + threadIdx.x; i < 1024 * 256; i += gridDim.x * 256) {
        int r = i >> 8;
        f32x4 v = {0.f, 0.f, 0.f, 0.f};
        if (r < nrows) v = ((const f32x4*)src)[i];
        h4 h, l;
        #pragma unroll
        for (int j = 0; j < 4; ++j) {
            _Float16 hh = (_Float16)v[j];
            h[j] = hh;
            if constexpr (LO) l[j] = (_Float16)((v[j] - (float)hh) * 2048.0f);
        }
        ((h4*)hi)[i] = h;
        if constexpr (LO) ((h4*)lo)[i] = l;
    }
}

// cT[n][k] = k<1000 ? fp16(centroid[k][n]) : 0
__global__ __launch_bounds__(256) void ctrans_kernel(const float* __restrict__ centroid,
                                                     _Float16* __restrict__ cT)
{
    __shared__ float tile[32][33];
    const int t = threadIdx.x;
    const int tx = t & 31, ty = t >> 5;
    const int k0 = blockIdx.y * 32, n0 = blockIdx.x * 32;
    #pragma unroll
    for (int p = 0; p < 4; ++p) {
        int k = k0 + ty + p * 8;
        tile[ty + p * 8][tx] = (k < 1000) ? centroid[(size_t)k * 1024 + n0 + tx] : 0.0f;
    }
    __syncthreads();
    #pragma unroll
    for (int p = 0; p < 4; ++p) {
        int n = n0 + ty + p * 8;
        cT[(size_t)n * 1024 + k0 + tx] = (_Float16)tile[tx][ty + p * 8];
    }
}

// shared device body: masked softmax given logits x (len 1000) -> fp16 row y
__device__ __forceinline__ void masked_softmax_body(
    const float* __restrict__ x, _Float16* __restrict__ y,
    int t, float* wv, int* wi, int* flag_row, int* d_idx, int* d_cnt, int rowid)
{
    // ---- top-2 (value) + argmax(first-occurrence) ----
    float bv = -1e30f, sv = -1e30f; int bi = 0;
    for (int c = t; c < 1000; c += 256) {
        float v = x[c];
        if (v > bv) { sv = bv; bv = v; bi = c; }
        else if (v > sv) sv = v;
    }
    #pragma unroll
    for (int off = 32; off > 0; off >>= 1) {
        float ov = __shfl_down(bv, off, 64);
        int   oi = __shfl_down(bi, off, 64);
        float os = __shfl_down(sv, off, 64);
        if (ov > bv || (ov == bv && oi < bi)) {
            sv = fmaxf(bv, os); bv = ov; bi = oi;
        } else {
            sv = fmaxf(sv, fmaxf(ov, os) == ov ? ov : os);
            sv = fmaxf(sv, ov); sv = fmaxf(sv, os);
        }
    }
    __shared__ float svv[4];
    const int lane = t & 63, wid = t >> 6;
    if (lane == 0) { wv[wid] = bv; wi[wid] = bi; svv[wid] = sv; }
    __syncthreads();
    __shared__ float s_m, s_tot; __shared__ int s_p;
    if (t == 0) {
        float mv = wv[0]; int mi = wi[0]; float m2 = svv[0];
        for (int w = 1; w < 4; ++w) {
            if (wv[w] > mv || (wv[w] == mv && wi[w] < mi)) {
                m2 = fmaxf(mv, svv[w]); mv = wv[w]; mi = wi[w];
            } else {
                m2 = fmaxf(m2, fmaxf(wv[w], svv[w]));
            }
        }
        s_p = mi; s_m = mv;
        if (flag_row && (mv - m2) < TAU) {     // ambiguous: queue precise recompute
            int slot = atomicAdd(d_cnt, 1);
            if (slot < CAP) d_idx[slot] = rowid;
        }
    }
    __syncthreads();
    const int p = s_p; const float m = s_m;
    if (p >= 500) {
        for (int c = t; c < 1024; c += 256) y[c] = (c == p) ? (_Float16)1.0f : (_Float16)0.0f;
    } else {
        float s = 0.f;
        for (int c = t; c < 1000; c += 256)
            if (c == p || c >= 500) s += expf(x[c] - m);
        #pragma unroll
        for (int off = 32; off > 0; off >>= 1) s += __shfl_down(s, off, 64);
        if (lane == 0) wv[wid] = s;
        __syncthreads();
        if (t == 0) s_tot = wv[0] + wv[1] + wv[2] + wv[3];
        __syncthreads();
        const float inv = 1.0f / s_tot;
        for (int c = t; c < 1024; c += 256) {
            float v = 0.f;
            if (c < 1000 && (c == p || c >= 500)) v = expf(x[c] - m) * inv;
            y[c] = (_Float16)v;
        }
    }
}

__global__ __launch_bounds__(256) void masksm_kernel(const float* __restrict__ o1,
                                                     _Float16* __restrict__ sm,
                                                     int* __restrict__ d_idx,
                                                     int* __restrict__ d_cnt)
{
    __shared__ float wv[4]; __shared__ int wi[4];
    const int row = blockIdx.x;
    int dummy;
    masked_softmax_body(o1 + (size_t)row * 1000, sm + (size_t)row * 1024,
                        threadIdx.x, wv, wi, &dummy, d_idx, d_cnt, row);
}

// precise rewrite of flagged rows from o1g
__global__ __launch_bounds__(256) void fixup_kernel(const float* __restrict__ o1g,
                                                    _Float16* __restrict__ sm,
                                                    const int* __restrict__ d_idx,
                                                    const int* __restrict__ d_cnt)
{
    const int slot = blockIdx.x;
    if (slot >= *d_cnt || slot >= CAP) return;
    const int row = d_idx[slot];
    __shared__ float wv[4]; __shared__ int wi[4];
    masked_softmax_body(o1g + (size_t)slot * 1000, sm + (size_t)row * 1024,
                        threadIdx.x, wv, wi, nullptr, nullptr, nullptr, 0);
}

// gather flagged feature rows -> fp16 hi/lo split [CAP x 2048]
__global__ __launch_bounds__(256) void gather_split_kernel(
    const float* __restrict__ features,
    _Float16* __restrict__ fgh, _Float16* __restrict__ fgl,
    const int* __restrict__ d_idx, const int* __restrict__ d_cnt)
{
    const int slot = blockIdx.x;
    if (slot >= *d_cnt || slot >= CAP) return;
    const int row = d_idx[slot];
    const int t = threadIdx.x;
    #pragma unroll
    for (int q = 0; q < 2; ++q) {
        int o = t * 8 + q * 4;   // 0..2047
        f32x4 v = *(const f32x4*)(features + (size_t)row * 2048 + o);
        h4 h, l;
        #pragma unroll
        for (int j = 0; j < 4; ++j) {
            _Float16 hh = (_Float16)v[j];
            h[j] = hh;
            l[j] = (_Float16)((v[j] - (float)hh) * 2048.0f);
        }
        *(h4*)(fgh + (size_t)slot * 2048 + o) = h;
        *(h4*)(fgl + (size_t)slot * 2048 + o) = l;
    }
}

// fused: invn = 1/max(||aug_row||,eps); xh = fp16(aug * invn)
__global__ __launch_bounds__(256) void rownorm_x_kernel(const float* __restrict__ aug,
                                                        _Float16* __restrict__ xh)
{
    const int row = blockIdx.x; const int t = threadIdx.x;
    f32x4 v = *((const f32x4*)(aug + (size_t)row * 1024) + t);
    float s = v[0]*v[0] + v[1]*v[1] + v[2]*v[2] + v[3]*v[3];
    #pragma unroll
    for (int off = 32; off > 0; off >>= 1) s += __shfl_down(s, off, 64);
    __shared__ float ws4[4]; __shared__ float s_inv;
    const int lane = t & 63, wid = t >> 6;
    if (lane == 0) ws4[wid] = s;
    __syncthreads();
    if (t == 0) {
        float tot = ws4[0] + ws4[1] + ws4[2] + ws4[3];
        s_inv = 1.0f / fmaxf(sqrtf(tot), 1e-12f);
    }
    __syncthreads();
    const float inv = s_inv;
    h4 h;
    #pragma unroll
    for (int j = 0; j < 4; ++j) h[j] = (_Float16)(v[j] * inv);
    *((h4*)(xh + (size_t)row * 1024) + t) = h;
}

// plain row softmax over 1000
__global__ __launch_bounds__(256) void softmax2_kernel(const float* __restrict__ o2,
                                                       float* __restrict__ out)
{
    const int row = blockIdx.x; const int t = threadIdx.x;
    const float* x = o2 + (size_t)row * 1000;
    float* y = out + (size_t)row * 1000;
    float m = -1e30f;
    for (int c = t; c < 1000; c += 256) m = fmaxf(m, x[c]);
    #pragma unroll
    for (int off = 32; off > 0; off >>= 1) m = fmaxf(m, __shfl_down(m, off, 64));
    __shared__ float sm4[4]; __shared__ float s_m, s_s;
    const int lane = t & 63, wid = t >> 6;
    if (lane == 0) sm4[wid] = m;
    __syncthreads();
    if (t == 0) s_m = fmaxf(fmaxf(sm4[0], sm4[1]), fmaxf(sm4[2], sm4[3]));
    __syncthreads();
    m = s_m;
    float s = 0.f;
    for (int c = t; c < 1000; c += 256) s += expf(x[c] - m);
    #pragma unroll
    for (int off = 32; off > 0; off >>= 1) s += __shfl_down(s, off, 64);
    if (lane == 0) sm4[wid] = s;
    __syncthreads();
    if (t == 0) s_s = sm4[0] + sm4[1] + sm4[2] + sm4[3];
    __syncthreads();
    const float inv = 1.0f / s_s;
    for (int c = t; c < 1000; c += 256) y[c] = expf(x[c] - m) * inv;
}

extern "C" void kernel_launch(void* const* d_in, const int* in_sizes, int n_in,
                              void* d_out, int out_size, void* d_ws, size_t ws_size,
                              hipStream_t stream)
{
    const float* features = (const float*)d_in[0];  // [8192,2048]
    const float* W_b      = (const float*)d_in[1];  // [1024,2048]
    const float* b_b      = (const float*)d_in[2];  // [1024]
    const float* W1       = (const float*)d_in[3];  // [1000,1024]
    const float* W2       = (const float*)d_in[4];  // [1000,1024]
    const float* centroid = (const float*)d_in[5];  // [1000,1024]

    char* base = (char*)d_out;
    float* feats = (float*)(base);
    float* aug   = (float*)(base + 33554432);
    float* o1    = (float*)(base + 67108864);
    float* o2    = (float*)(base + 99876864);
    float* smx   = (float*)(base + 132644864);

    _Float16* fh    = (_Float16*)(base + 67108864);
    _Float16* fetsh = (_Float16*)(base + 33554432);
    int*      idx   = (int*)     (base + 50331648);
    int*      cnt   = (int*)     (base + 50339840);
    _Float16* fgsh  = (_Float16*)(base + 50348032);
    _Float16* fgsl  = (_Float16*)(base + 54542336);
    float*    o1g   = (float*)   (base + 58736640);
    _Float16* sm1h  = (_Float16*)(base + 99876864);
    _Float16* cth   = (_Float16*)(base + 116654080);
    _Float16* wbh   = (_Float16*)(base + 118751232);
    _Float16* wbl   = (_Float16*)(base + 122945536);
    _Float16* w2h   = (_Float16*)(base + 132644864);
    _Float16* w1h   = (_Float16*)(base + 142606336);
    _Float16* w1l   = (_Float16*)(base + 144703488);
    _Float16* fgh   = (_Float16*)(base + 146800640);
    _Float16* fgl   = (_Float16*)(base + 155189248);
    _Float16* xh    = (_Float16*)(base + 146800640);

    zero_cnt_kernel<<<1, 1, 0, stream>>>(cnt);

    // conversions
    conv_kernel<<<2048, 256, 0, stream>>>(features, fh, 4194304);
    split_kernel<<<1024, 256, 0, stream>>>(W_b, wbh, wbl, 524288);
    padsplit_kernel<true><<<1024, 256, 0, stream>>>(W1, w1h, w1l, 1000);
    ctrans_kernel<<<dim3(32, 32), 256, 0, stream>>>(centroid, cth);
    padsplit_kernel<false><<<1024, 256, 0, stream>>>(W2, w2h, nullptr, 1000);

    // G1: feats = F@W_b^T + b_b (fp16x1); epilogue also emits fetsh
    gemm16<1><<<512, 256, 0, stream>>>(fh, nullptr, 2048, wbh, nullptr, 2048, 2048,
                                       feats, 1024, 1024, b_b, fetsh, nullptr, nullptr);
    // G2: o1 = feats@W1^T (fp16x1)
    gemm16<2><<<512, 256, 0, stream>>>(fetsh, nullptr, 1024, w1h, nullptr, 1024, 1024,
                                       o1, 1000, 1000, nullptr, nullptr, nullptr, nullptr);
    // masked softmax + ambiguity flagging
    masksm_kernel<<<8192, 256, 0, stream>>>(o1, sm1h, idx, cnt);

    // correction chain (flagged rows only; blocks early-exit on cnt)
    gather_split_kernel<<<CAP, 256, 0, stream>>>(features, fgh, fgl, idx, cnt);
    gemm16<5><<<dim3(8, CAP / 128), 256, 0, stream>>>(fgh, fgl, 2048, wbh, wbl, 2048, 2048,
                                                      nullptr, 0, 1024, b_b, fgsh, fgsl, cnt);
    gemm16<6><<<dim3(8, CAP / 128), 256, 0, stream>>>(fgsh, fgsl, 1024, w1h, w1l, 1024, 1024,
                                                      o1g, 1000, 1000, nullptr, nullptr, nullptr, cnt);
    fixup_kernel<<<CAP, 256, 0, stream>>>(o1g, sm1h, idx, cnt);

    // G3: aug = sm1@centroid + feats (fp16x1)
    gemm16<3><<<512, 256, 0, stream>>>(sm1h, nullptr, 1024, cth, nullptr, 1024, 1024,
                                       aug, 1024, 1024, feats, nullptr, nullptr, nullptr);
    rownorm_x_kernel<<<8192, 256, 0, stream>>>(aug, xh);
    // G4: o2 = x@W2^T * 20 (fp16x1)
    gemm16<4><<<512, 256, 0, stream>>>(xh, nullptr, 1024, w2h, nullptr, 1024, 1024,
                                       o2, 1000, 1000, nullptr, nullptr, nullptr, nullptr);
    softmax2_kernel<<<8192, 256, 0, stream>>>(o2, smx);
}

// Round 6
// 307.664 us; speedup vs baseline: 1.1762x; 1.1744x over previous
//
#include <hip/hip_runtime.h>
#include <cmath>

// ---------------------------------------------------------------------------
// Classifier pipeline. Main GEMMs fp16x1 (m97 structure); argmax protected by
// fp16x2 correction chain on flagged rows (top-2 gap < TAU), K-SPLIT over
// blockIdx.z to kill the low-block-count latency tail (round-5 lesson:
// 48 blocks x full-K ~ 85us regardless of total work).
//
// d_out byte layout (total 165,412,864 B):
//   feats [8192,1024] f32 @ 0
//   aug   [8192,1024] f32 @ 33,554,432
//   o1    [8192,1000] f32 @ 67,108,864
//   o2    [8192,1000] f32 @ 99,876,864
//   smx   [8192,1000] f32 @ 132,644,864
//
// Scratch (dead-region hosted; lifetime [first-write .. last-read]):
//   fh    fp16[8192*2048] @  67,108,864  [convF .. G1]       (o1 slot)
//   fetsh fp16[8192*1024] @  33,554,432  [G1 .. G2]          (aug slot)
//   P1    f32[4*1024*1024]@  33,554,432  [gG1 .. red1]       (aug slot, after fetsh dead)
//   P2    f32[2*1024*1000]@  33,554,432  [gG2 .. red2]       (aug slot, after P1 dead)
//   idx   int[1024]       @  50,331,648  [masksm .. fixup]
//   cnt   int             @  50,339,840  [zero .. fixup]
//   fgsh  fp16[1024*1024] @  50,348,032  [red1 .. gG2]
//   fgsl  fp16[1024*1024] @  52,445,184  [red1 .. gG2]
//   o1g   f32 [1024*1000] @  54,542,336  [red2 .. fixup]     (ends 58,638,336 < 67,108,864)
//   sm1h  fp16[8192*1024] @  99,876,864  [masksm .. G3]      (o2 slot)
//   cth   fp16[1024*1024] @ 116,654,080  [ctrans .. G3]
//   wbh   fp16[1024*2048] @ 118,751,232  [splitWb .. gG1]
//   wbl   fp16[1024*2048] @ 122,945,536  [splitWb .. gG1]    (ends 127,139,840)
//   w2h   fp16[1024*1024] @ 132,644,864  [padW2 .. G4]       (smx slot)
//   w1h   fp16[1024*1024] @ 142,606,336  [padW1 .. gG2]
//   w1l   fp16[1024*1024] @ 144,703,488  [padW1 .. gG2]
//   fgh   fp16[1024*2048] @ 146,800,640  [gather .. gG1]
//   fgl   fp16[1024*2048] @ 150,994,944  [gather .. gG1]     (ends 155,189,248)
//   xh    fp16[8192*1024] @ 146,800,640  [rownorm .. G4]     (overlaps dead fgh/fgl)
// ---------------------------------------------------------------------------

typedef _Float16 h8 __attribute__((ext_vector_type(8)));
typedef _Float16 h4 __attribute__((ext_vector_type(4)));
typedef float f32x4 __attribute__((ext_vector_type(4)));

#define TAU 0.015f
#define CAP 1024

__device__ __forceinline__ void gload_lds16(const _Float16* g, _Float16* l) {
    __builtin_amdgcn_global_load_lds(
        (const __attribute__((address_space(1))) void*)g,
        (__attribute__((address_space(3))) void*)l, 16, 0, 0);
}

__global__ void zero_cnt_kernel(int* __restrict__ cnt) { *cnt = 0; }

// MODE 1: fp16x1  C = A@B^T + bias(aux); also Ch=fp16(C)         (main G1)
// MODE 2: fp16x1  C = A@B^T, cols<nC                             (main G2)
// MODE 3: fp16x1  C = A@B^T + aux[row,col]                       (main G3)
// MODE 4: fp16x1  C = A@B^T * 20, cols<nC                        (main G4)
// MODE 5: fp16x2  partial: C[z] = A@B^T over K-chunk z, early-exit on cnt
template <int MODE>
__global__ __launch_bounds__(256, (MODE >= 5) ? 2 : 4) void gemm16(
    const _Float16* __restrict__ Ah, const _Float16* __restrict__ Al, int lda,
    const _Float16* __restrict__ Bh, const _Float16* __restrict__ Bl, int ldb,
    int klen,
    float* __restrict__ C, int ldc, int nC,
    const float* __restrict__ aux,
    _Float16* __restrict__ Ch,
    const int* __restrict__ cnt)
{
    constexpr bool P2 = (MODE >= 5);
    __shared__ _Float16 sAh[128 * 64];
    __shared__ _Float16 sBh[128 * 64];
    __shared__ _Float16 sAl[P2 ? 128 * 64 : 8];
    __shared__ _Float16 sBl[P2 ? 128 * 64 : 8];

    const int t = threadIdx.x;
    const int lane = t & 63, wid = t >> 6;
    int row0, col0, kbase;
    if constexpr (MODE >= 5) {
        row0 = blockIdx.y * 128; col0 = blockIdx.x * 128;
        kbase = blockIdx.z * klen;
        if (row0 >= *cnt) return;              // correction rows only
    } else {
        // T1: bijective XCD swizzle (512 wgs, 64/XCD -> 8 row-panels x 8 col)
        const int wg = blockIdx.x;
        const int wgid = (wg & 7) * 64 + (wg >> 3);
        row0 = (wgid >> 3) * 128; col0 = (wgid & 7) * 128;
        kbase = 0;
    }
    const int wr = wid >> 1, wc = wid & 1;     // 2x2 waves -> 64x64 out each
    const int fr = lane & 15;
    const int fk = (lane >> 4) * 8;
    const int srow = lane >> 3;                // staging: 8 lanes/row
    const int scol = (lane & 7) * 8;           // 16B per lane

    f32x4 acc[4][4] = {};
    f32x4 accc[4][4] = {};                     // cross terms (x2048); DCE'd if !P2

    for (int k0 = kbase; k0 < kbase + klen; k0 += 64) {
        #pragma unroll
        for (int j = 0; j < 4; ++j) {
            int i = wid * 4 + j;
            int r = i * 8 + srow;
            const size_t ga = (size_t)(row0 + r) * lda + k0 + scol;
            const size_t gb = (size_t)(col0 + r) * ldb + k0 + scol;
            gload_lds16(Ah + ga, &sAh[i * 512]);
            gload_lds16(Bh + gb, &sBh[i * 512]);
            if constexpr (P2) {
                gload_lds16(Al + ga, &sAl[i * 512]);
                gload_lds16(Bl + gb, &sBl[i * 512]);
            }
        }
        __syncthreads();
        #pragma unroll
        for (int ks = 0; ks < 2; ++ks) {
            h8 ah[4], al[4];
            #pragma unroll
            for (int mf = 0; mf < 4; ++mf) {
                int rr = wr * 64 + mf * 16 + fr;
                ah[mf] = *(const h8*)&sAh[rr * 64 + ks * 32 + fk];
                if constexpr (P2) al[mf] = *(const h8*)&sAl[rr * 64 + ks * 32 + fk];
            }
            #pragma unroll
            for (int nf = 0; nf < 4; ++nf) {
                int cc = wc * 64 + nf * 16 + fr;
                h8 bh = *(const h8*)&sBh[cc * 64 + ks * 32 + fk];
                h8 bl;
                if constexpr (P2) bl = *(const h8*)&sBl[cc * 64 + ks * 32 + fk];
                #pragma unroll
                for (int mf = 0; mf < 4; ++mf) {
                    acc[mf][nf] = __builtin_amdgcn_mfma_f32_16x16x32_f16(ah[mf], bh, acc[mf][nf], 0, 0, 0);
                    if constexpr (P2) {
                        accc[mf][nf] = __builtin_amdgcn_mfma_f32_16x16x32_f16(ah[mf], bl, accc[mf][nf], 0, 0, 0);
                        accc[mf][nf] = __builtin_amdgcn_mfma_f32_16x16x32_f16(al[mf], bh, accc[mf][nf], 0, 0, 0);
                    }
                }
            }
        }
        __syncthreads();
    }
    // ---- epilogue (C/D: col=lane&15, row=(lane>>4)*4+j) ----
    float* Cz = C;
    if constexpr (MODE >= 5) Cz = C + (size_t)blockIdx.z * CAP * ldc;
    #pragma unroll
    for (int mf = 0; mf < 4; ++mf) {
        #pragma unroll
        for (int nf = 0; nf < 4; ++nf) {
            f32x4 v = acc[mf][nf];
            if constexpr (P2) v = v + accc[mf][nf] * (1.0f / 2048.0f);
            const int gcol = col0 + wc * 64 + nf * 16 + fr;
            const int rbase = row0 + wr * 64 + mf * 16 + (lane >> 4) * 4;
            #pragma unroll
            for (int j = 0; j < 4; ++j) {
                const int grow = rbase + j;
                float val = v[j];
                if constexpr (MODE == 1) val += aux[gcol];
                if constexpr (MODE == 3) val += aux[(size_t)grow * 1024 + gcol];
                if constexpr (MODE == 4) val *= 20.0f;
                if (gcol < nC) {
                    Cz[(size_t)grow * ldc + gcol] = val;
                    if constexpr (MODE == 1)
                        Ch[(size_t)grow * 1024 + gcol] = (_Float16)val;
                }
            }
        }
    }
}

// fp32 -> fp16 (hi only)
__global__ void conv_kernel(const float* __restrict__ src, _Float16* __restrict__ hi, int n4)
{
    for (int i = blockIdx.x * 256 + threadIdx.x; i < n4; i += gridDim.x * 256) {
        f32x4 v = ((const f32x4*)src)[i];
        h4 h;
        #pragma unroll
        for (int j = 0; j < 4; ++j) h[j] = (_Float16)v[j];
        ((h4*)hi)[i] = h;
    }
}

// fp32 -> fp16 hi/lo split (lo scaled x2048)
__global__ void split_kernel(const float* __restrict__ src,
                             _Float16* __restrict__ hi, _Float16* __restrict__ lo, int n4)
{
    for (int i = blockIdx.x * 256 + threadIdx.x; i < n4; i += gridDim.x * 256) {
        f32x4 v = ((const f32x4*)src)[i];
        h4 h, l;
        #pragma unroll
        for (int j = 0; j < 4; ++j) {
            _Float16 hh = (_Float16)v[j];
            h[j] = hh;
            l[j] = (_Float16)((v[j] - (float)hh) * 2048.0f);
        }
        ((h4*)hi)[i] = h;
        ((h4*)lo)[i] = l;
    }
}

// fp32 [nrows,1024] -> fp16 hi(/lo) padded to [1024,1024]
template <bool LO>
__global__ void padsplit_kernel(const float* __restrict__ src,
                                _Float16* __restrict__ hi, _Float16* __restrict__ lo, int nrows)
{
    for (int i = blockIdx.x * 256 + threadIdx.x; i < 1024 * 256; i += gridDim.x * 256) {
        int r = i >> 8;
        f32x4 v = {0.f, 0.f, 0.f, 0.f};
        if (r < nrows) v = ((const f32x4*)src)[i];
        h4 h, l;
        #pragma unroll
        for (int j = 0; j < 4; ++j) {
            _Float16 hh = (_Float16)v[j];
            h[j] = hh;
            if constexpr (LO) l[j] = (_Float16)((v[j] - (float)hh) * 2048.0f);
        }
        ((h4*)hi)[i] = h;
        if constexpr (LO) ((h4*)lo)[i] = l;
    }
}

// cT[n][k] = k<1000 ? fp16(centroid[k][n]) : 0
__global__ __launch_bounds__(256) void ctrans_kernel(const float* __restrict__ centroid,
                                                     _Float16* __restrict__ cT)
{
    __shared__ float tile[32][33];
    const int t = threadIdx.x;
    const int tx = t & 31, ty = t >> 5;
    const int k0 = blockIdx.y * 32, n0 = blockIdx.x * 32;
    #pragma unroll
    for (int p = 0; p < 4; ++p) {
        int k = k0 + ty + p * 8;
        tile[ty + p * 8][tx] = (k < 1000) ? centroid[(size_t)k * 1024 + n0 + tx] : 0.0f;
    }
    __syncthreads();
    #pragma unroll
    for (int p = 0; p < 4; ++p) {
        int n = n0 + ty + p * 8;
        cT[(size_t)n * 1024 + k0 + tx] = (_Float16)tile[tx][ty + p * 8];
    }
}

// shared device body: masked softmax given logits x (len 1000) -> fp16 row y
__device__ __forceinline__ void masked_softmax_body(
    const float* __restrict__ x, _Float16* __restrict__ y,
    int t, float* wv, int* wi, bool flag, int* d_idx, int* d_cnt, int rowid)
{
    // ---- top-2 (value) + argmax(first-occurrence) ----
    float bv = -1e30f, sv = -1e30f; int bi = 0;
    for (int c = t; c < 1000; c += 256) {
        float v = x[c];
        if (v > bv) { sv = bv; bv = v; bi = c; }
        else if (v > sv) sv = v;
    }
    #pragma unroll
    for (int off = 32; off > 0; off >>= 1) {
        float ov = __shfl_down(bv, off, 64);
        int   oi = __shfl_down(bi, off, 64);
        float os = __shfl_down(sv, off, 64);
        if (ov > bv || (ov == bv && oi < bi)) {
            sv = fmaxf(bv, os); bv = ov; bi = oi;
        } else {
            sv = fmaxf(sv, fmaxf(ov, os) == ov ? ov : os);
            sv = fmaxf(sv, ov); sv = fmaxf(sv, os);
        }
    }
    __shared__ float svv[4];
    const int lane = t & 63, wid = t >> 6;
    if (lane == 0) { wv[wid] = bv; wi[wid] = bi; svv[wid] = sv; }
    __syncthreads();
    __shared__ float s_m, s_tot; __shared__ int s_p;
    if (t == 0) {
        float mv = wv[0]; int mi = wi[0]; float m2 = svv[0];
        for (int w = 1; w < 4; ++w) {
            if (wv[w] > mv || (wv[w] == mv && wi[w] < mi)) {
                m2 = fmaxf(mv, svv[w]); mv = wv[w]; mi = wi[w];
            } else {
                m2 = fmaxf(m2, fmaxf(wv[w], svv[w]));
            }
        }
        s_p = mi; s_m = mv;
        if (flag && (mv - m2) < TAU) {         // ambiguous: queue precise recompute
            int slot = atomicAdd(d_cnt, 1);
            if (slot < CAP) d_idx[slot] = rowid;
        }
    }
    __syncthreads();
    const int p = s_p; const float m = s_m;
    if (p >= 500) {
        for (int c = t; c < 1024; c += 256) y[c] = (c == p) ? (_Float16)1.0f : (_Float16)0.0f;
    } else {
        float s = 0.f;
        for (int c = t; c < 1000; c += 256)
            if (c == p || c >= 500) s += expf(x[c] - m);
        #pragma unroll
        for (int off = 32; off > 0; off >>= 1) s += __shfl_down(s, off, 64);
        if (lane == 0) wv[wid] = s;
        __syncthreads();
        if (t == 0) s_tot = wv[0] + wv[1] + wv[2] + wv[3];
        __syncthreads();
        const float inv = 1.0f / s_tot;
        for (int c = t; c < 1024; c += 256) {
            float v = 0.f;
            if (c < 1000 && (c == p || c >= 500)) v = expf(x[c] - m) * inv;
            y[c] = (_Float16)v;
        }
    }
}

__global__ __launch_bounds__(256) void masksm_kernel(const float* __restrict__ o1,
                                                     _Float16* __restrict__ sm,
                                                     int* __restrict__ d_idx,
                                                     int* __restrict__ d_cnt)
{
    __shared__ float wv[4]; __shared__ int wi[4];
    const int row = blockIdx.x;
    masked_softmax_body(o1 + (size_t)row * 1000, sm + (size_t)row * 1024,
                        threadIdx.x, wv, wi, true, d_idx, d_cnt, row);
}

// precise rewrite of flagged rows from o1g
__global__ __launch_bounds__(256) void fixup_kernel(const float* __restrict__ o1g,
                                                    _Float16* __restrict__ sm,
                                                    const int* __restrict__ d_idx,
                                                    const int* __restrict__ d_cnt)
{
    const int slot = blockIdx.x;
    if (slot >= *d_cnt || slot >= CAP) return;
    const int row = d_idx[slot];
    __shared__ float wv[4]; __shared__ int wi[4];
    masked_softmax_body(o1g + (size_t)slot * 1000, sm + (size_t)row * 1024,
                        threadIdx.x, wv, wi, false, nullptr, nullptr, 0);
}

// gather flagged feature rows -> fp16 hi/lo split [CAP x 2048]
__global__ __launch_bounds__(256) void gather_split_kernel(
    const float* __restrict__ features,
    _Float16* __restrict__ fgh, _Float16* __restrict__ fgl,
    const int* __restrict__ d_idx, const int* __restrict__ d_cnt)
{
    const int slot = blockIdx.x;
    if (slot >= *d_cnt || slot >= CAP) return;
    const int row = d_idx[slot];
    const int t = threadIdx.x;
    #pragma unroll
    for (int q = 0; q < 2; ++q) {
        int o = t * 8 + q * 4;   // 0..2047
        f32x4 v = *(const f32x4*)(features + (size_t)row * 2048 + o);
        h4 h, l;
        #pragma unroll
        for (int j = 0; j < 4; ++j) {
            _Float16 hh = (_Float16)v[j];
            h[j] = hh;
            l[j] = (_Float16)((v[j] - (float)hh) * 2048.0f);
        }
        *(h4*)(fgh + (size_t)slot * 2048 + o) = h;
        *(h4*)(fgl + (size_t)slot * 2048 + o) = l;
    }
}

// red1: fgs = split( sum_z P1[z] + bias )   (per flagged slot, 1024 cols)
__global__ __launch_bounds__(256) void red1_kernel(const float* __restrict__ P1,
                                                   const float* __restrict__ bias,
                                                   _Float16* __restrict__ fgsh,
                                                   _Float16* __restrict__ fgsl,
                                                   const int* __restrict__ d_cnt)
{
    const int slot = blockIdx.x;
    if (slot >= *d_cnt || slot >= CAP) return;
    const int t = threadIdx.x;
    #pragma unroll
    for (int q = 0; q < 4; ++q) {
        const int c = t + q * 256;
        const size_t o = (size_t)slot * 1024 + c;
        float s = P1[o] + P1[o + (size_t)CAP * 1024] + P1[o + (size_t)2 * CAP * 1024]
                + P1[o + (size_t)3 * CAP * 1024] + bias[c];
        _Float16 h = (_Float16)s;
        fgsh[o] = h;
        fgsl[o] = (_Float16)((s - (float)h) * 2048.0f);
    }
}

// red2: o1g = P2[0] + P2[1]   (per flagged slot, 1000 cols)
__global__ __launch_bounds__(256) void red2_kernel(const float* __restrict__ P2,
                                                   float* __restrict__ o1g,
                                                   const int* __restrict__ d_cnt)
{
    const int slot = blockIdx.x;
    if (slot >= *d_cnt || slot >= CAP) return;
    const int t = threadIdx.x;
    for (int c = t; c < 1000; c += 256) {
        const size_t o = (size_t)slot * 1000 + c;
        o1g[o] = P2[o] + P2[o + (size_t)CAP * 1000];
    }
}

// fused: invn = 1/max(||aug_row||,eps); xh = fp16(aug * invn)
__global__ __launch_bounds__(256) void rownorm_x_kernel(const float* __restrict__ aug,
                                                        _Float16* __restrict__ xh)
{
    const int row = blockIdx.x; const int t = threadIdx.x;
    f32x4 v = *((const f32x4*)(aug + (size_t)row * 1024) + t);
    float s = v[0]*v[0] + v[1]*v[1] + v[2]*v[2] + v[3]*v[3];
    #pragma unroll
    for (int off = 32; off > 0; off >>= 1) s += __shfl_down(s, off, 64);
    __shared__ float ws4[4]; __shared__ float s_inv;
    const int lane = t & 63, wid = t >> 6;
    if (lane == 0) ws4[wid] = s;
    __syncthreads();
    if (t == 0) {
        float tot = ws4[0] + ws4[1] + ws4[2] + ws4[3];
        s_inv = 1.0f / fmaxf(sqrtf(tot), 1e-12f);
    }
    __syncthreads();
    const float inv = s_inv;
    h4 h;
    #pragma unroll
    for (int j = 0; j < 4; ++j) h[j] = (_Float16)(v[j] * inv);
    *((h4*)(xh + (size_t)row * 1024) + t) = h;
}

// plain row softmax over 1000
__global__ __launch_bounds__(256) void softmax2_kernel(const float* __restrict__ o2,
                                                       float* __restrict__ out)
{
    const int row = blockIdx.x; const int t = threadIdx.x;
    const float* x = o2 + (size_t)row * 1000;
    float* y = out + (size_t)row * 1000;
    float m = -1e30f;
    for (int c = t; c < 1000; c += 256) m = fmaxf(m, x[c]);
    #pragma unroll
    for (int off = 32; off > 0; off >>= 1) m = fmaxf(m, __shfl_down(m, off, 64));
    __shared__ float sm4[4]; __shared__ float s_m, s_s;
    const int lane = t & 63, wid = t >> 6;
    if (lane == 0) sm4[wid] = m;
    __syncthreads();
    if (t == 0) s_m = fmaxf(fmaxf(sm4[0], sm4[1]), fmaxf(sm4[2], sm4[3]));
    __syncthreads();
    m = s_m;
    float s = 0.f;
    for (int c = t; c < 1000; c += 256) s += expf(x[c] - m);
    #pragma unroll
    for (int off = 32; off > 0; off >>= 1) s += __shfl_down(s, off, 64);
    if (lane == 0) sm4[wid] = s;
    __syncthreads();
    if (t == 0) s_s = sm4[0] + sm4[1] + sm4[2] + sm4[3];
    __syncthreads();
    const float inv = 1.0f / s_s;
    for (int c = t; c < 1000; c += 256) y[c] = expf(x[c] - m) * inv;
}

extern "C" void kernel_launch(void* const* d_in, const int* in_sizes, int n_in,
                              void* d_out, int out_size, void* d_ws, size_t ws_size,
                              hipStream_t stream)
{
    const float* features = (const float*)d_in[0];  // [8192,2048]
    const float* W_b      = (const float*)d_in[1];  // [1024,2048]
    const float* b_b      = (const float*)d_in[2];  // [1024]
    const float* W1       = (const float*)d_in[3];  // [1000,1024]
    const float* W2       = (const float*)d_in[4];  // [1000,1024]
    const float* centroid = (const float*)d_in[5];  // [1000,1024]

    char* base = (char*)d_out;
    float* feats = (float*)(base);
    float* aug   = (float*)(base + 33554432);
    float* o1    = (float*)(base + 67108864);
    float* o2    = (float*)(base + 99876864);
    float* smx   = (float*)(base + 132644864);

    _Float16* fh    = (_Float16*)(base + 67108864);
    _Float16* fetsh = (_Float16*)(base + 33554432);
    float*    P1    = (float*)   (base + 33554432);
    float*    P2    = (float*)   (base + 33554432);
    int*      idx   = (int*)     (base + 50331648);
    int*      cnt   = (int*)     (base + 50339840);
    _Float16* fgsh  = (_Float16*)(base + 50348032);
    _Float16* fgsl  = (_Float16*)(base + 52445184);
    float*    o1g   = (float*)   (base + 54542336);
    _Float16* sm1h  = (_Float16*)(base + 99876864);
    _Float16* cth   = (_Float16*)(base + 116654080);
    _Float16* wbh   = (_Float16*)(base + 118751232);
    _Float16* wbl   = (_Float16*)(base + 122945536);
    _Float16* w2h   = (_Float16*)(base + 132644864);
    _Float16* w1h   = (_Float16*)(base + 142606336);
    _Float16* w1l   = (_Float16*)(base + 144703488);
    _Float16* fgh   = (_Float16*)(base + 146800640);
    _Float16* fgl   = (_Float16*)(base + 150994944);
    _Float16* xh    = (_Float16*)(base + 146800640);

    zero_cnt_kernel<<<1, 1, 0, stream>>>(cnt);

    // conversions
    conv_kernel<<<2048, 256, 0, stream>>>(features, fh, 4194304);
    split_kernel<<<1024, 256, 0, stream>>>(W_b, wbh, wbl, 524288);
    padsplit_kernel<true><<<1024, 256, 0, stream>>>(W1, w1h, w1l, 1000);
    ctrans_kernel<<<dim3(32, 32), 256, 0, stream>>>(centroid, cth);
    padsplit_kernel<false><<<1024, 256, 0, stream>>>(W2, w2h, nullptr, 1000);

    // G1: feats = F@W_b^T + b_b (fp16x1); epilogue also emits fetsh
    gemm16<1><<<512, 256, 0, stream>>>(fh, nullptr, 2048, wbh, nullptr, 2048, 2048,
                                       feats, 1024, 1024, b_b, fetsh, nullptr);
    // G2: o1 = feats@W1^T (fp16x1)
    gemm16<2><<<512, 256, 0, stream>>>(fetsh, nullptr, 1024, w1h, nullptr, 1024, 1024,
                                       o1, 1000, 1000, nullptr, nullptr, nullptr);
    // masked softmax + ambiguity flagging
    masksm_kernel<<<8192, 256, 0, stream>>>(o1, sm1h, idx, cnt);

    // correction chain (flagged rows only; blocks early-exit on cnt)
    gather_split_kernel<<<CAP, 256, 0, stream>>>(features, fgh, fgl, idx, cnt);
    // gG1 partials: P1[z] = Fg @ W_b^T over K-chunk z (4 x 512)
    gemm16<5><<<dim3(8, CAP / 128, 4), 256, 0, stream>>>(fgh, fgl, 2048, wbh, wbl, 2048, 512,
                                                         P1, 1024, 1024, nullptr, nullptr, cnt);
    red1_kernel<<<CAP, 256, 0, stream>>>(P1, b_b, fgsh, fgsl, cnt);
    // gG2 partials: P2[z] = fgs @ W1^T over K-chunk z (2 x 512)
    gemm16<5><<<dim3(8, CAP / 128, 2), 256, 0, stream>>>(fgsh, fgsl, 1024, w1h, w1l, 1024, 512,
                                                         P2, 1000, 1000, nullptr, nullptr, cnt);
    red2_kernel<<<CAP, 256, 0, stream>>>(P2, o1g, cnt);
    fixup_kernel<<<CAP, 256, 0, stream>>>(o1g, sm1h, idx, cnt);

    // G3: aug = sm1@centroid + feats (fp16x1)
    gemm16<3><<<512, 256, 0, stream>>>(sm1h, nullptr, 1024, cth, nullptr, 1024, 1024,
                                       aug, 1024, 1024, feats, nullptr, nullptr);
    rownorm_x_kernel<<<8192, 256, 0, stream>>>(aug, xh);
    // G4: o2 = x@W2^T * 20 (fp16x1)
    gemm16<4><<<512, 256, 0, stream>>>(xh, nullptr, 1024, w2h, nullptr, 1024, 1024,
                                       o2, 1000, 1000, nullptr, nullptr, nullptr);
    softmax2_kernel<<<8192, 256, 0, stream>>>(o2, smx);
}